// Round 5
// baseline (7593.172 us; speedup 1.0000x reference)
//
#include <hip/hip_runtime.h>
#include <hip/hip_bf16.h>

// LSTM H=1024, B=256, T=256, C=10 — round 5.
// Rounds 2-4 failed with absmax EXACTLY (max|ref| - 1/256): the persistent
// kernel never ran (hipLaunchCooperativeKernel error, silently swallowed);
// lstm_final ran on 0xAA-poisoned hfin -> uniform softmax 1/256.
// Fix: REGULAR launch of the persistent kernel (256 WGs <= 256 CUs, all
// co-resident by capacity: ~330 VGPR < 512 @ 1 wave/SIMD, 49 KB LDS < 160 KB)
// + per-bt-group atomic counter barrier with explicit fences:
//   producer: stores -> __threadfence() (all threads) -> __syncthreads()
//             -> tid0 release-fetch_add (agent scope)
//   consumer: tid0 acquire-load spin -> __syncthreads() -> plain reads.
// Compute core: round-4 16x16x32 fragment maps (HW-verified, round-1-proven).

#define H 1024
#define B 256
#define T 256
#define NCLS 10

typedef __attribute__((ext_vector_type(8))) short short8;   // 8 bf16
typedef __attribute__((ext_vector_type(4))) float f32x4;

__device__ inline unsigned short bf16_bits(float f) {
    union { __hip_bfloat16 h; unsigned short u; } cv;
    cv.h = __float2bfloat16(f);
    return cv.u;
}

// h frag layout (per 512 KB buffer), 16x16x32 B-frag order:
//   short index of (j in [0,1024), b in [0,256)):
//   ((b>>4)*32 + (j>>5))*512 + (((j>>3)&3)*16 + (b&15))*8 + (j&7)

__global__ __launch_bounds__(256, 1) void lstm_persist(
    const float* __restrict__ x,
    const float* __restrict__ Wgh, const float* __restrict__ Wih,
    const float* __restrict__ Wfh, const float* __restrict__ Woh,
    const float* __restrict__ Wgx, const float* __restrict__ Wix,
    const float* __restrict__ Wfx, const float* __restrict__ Wox,
    const float* __restrict__ bg, const float* __restrict__ bi,
    const float* __restrict__ bf_, const float* __restrict__ bo,
    char* __restrict__ frag,            // 2 x 524288 bytes
    unsigned* __restrict__ cnt,         // 8 group counters, 128 B apart
    float* __restrict__ hfin)           // H x B fp32
{
    __shared__ __align__(16) char hstage[32768];   // half-K of the bt h-slice
    __shared__ float zbuf[4][32][32];
    __shared__ float wxl[4][32];
    __shared__ float bsl[4][32];

    const int tid  = threadIdx.x;
    const int lane = tid & 63;
    const int wave = tid >> 6;
    const int bt = blockIdx.x & 7;       // column group (XCD-local heuristic)
    const int jt = blockIdx.x >> 3;
    const int j0 = jt * 32;
    const int b0 = bt * 32;

    if (tid < 128) {
        int g = tid >> 5, r = tid & 31;
        const float* wx = (g == 0) ? Wgx : (g == 1) ? Wix : (g == 2) ? Wfx : Wox;
        const float* bb = (g == 0) ? bg  : (g == 1) ? bi  : (g == 2) ? bf_ : bo;
        wxl[g][r] = wx[j0 + r];
        bsl[g][r] = bb[b0 + r];
    }

    // ---- one-time: W gate tile -> registers, 16x16x32 A-fragment order ----
    // A map (HW-verified): lane holds A[m=lane&15][k = c*32 + (lane>>4)*8 + i]
    const float* Wh = (wave == 0) ? Wgh : (wave == 1) ? Wih : (wave == 2) ? Wfh : Woh;
    short8 awreg[2][32];
#pragma unroll
    for (int mt = 0; mt < 2; ++mt) {
        const float* wrow = Wh + (j0 + 16 * mt + (lane & 15)) * H + ((lane >> 4) * 8);
#pragma unroll
        for (int c = 0; c < 32; ++c) {
            const float4 f0 = *(const float4*)(wrow + c * 32);
            const float4 f1 = *(const float4*)(wrow + c * 32 + 4);
            short8 s;
            s[0] = (short)bf16_bits(f0.x); s[1] = (short)bf16_bits(f0.y);
            s[2] = (short)bf16_bits(f0.z); s[3] = (short)bf16_bits(f0.w);
            s[4] = (short)bf16_bits(f1.x); s[5] = (short)bf16_bits(f1.y);
            s[6] = (short)bf16_bits(f1.z); s[7] = (short)bf16_bits(f1.w);
            awreg[mt][c] = s;
        }
    }

    float creg[4] = {0.f, 0.f, 0.f, 0.f};
    const int nn = tid & 31;       // epilogue column
    const int aa = tid >> 5;       // epilogue j-quad index
    unsigned* myc = &cnt[bt * 32];

    for (int t = 0; t < T; ++t) {
        // ---- wait: all 32 WGs of this bt-group finished step t-1 ----
        if (tid == 0) {
            const unsigned target = 32u * (unsigned)t;
            while (__hip_atomic_load(myc, __ATOMIC_ACQUIRE, __HIP_MEMORY_SCOPE_AGENT) < target)
                __builtin_amdgcn_s_sleep(2);
        }
        __syncthreads();

        const char* gslice = frag + (t & 1) * 524288 + bt * 65536;

        f32x4 a00 = {0.f,0.f,0.f,0.f}, a01 = a00, a10 = a00, a11 = a00;

#pragma unroll
        for (int ph = 0; ph < 2; ++ph) {
            // stage k-half: 16 KB from each of the 2 n-tile blocks
            {
                const short8* s0 = (const short8*)(gslice + 0 * 32768 + ph * 16384);
                const short8* s1 = (const short8*)(gslice + 1 * 32768 + ph * 16384);
                short8* d = (short8*)hstage;
                for (int i = tid; i < 1024; i += 256) d[i] = s0[i];
                for (int i = tid; i < 1024; i += 256) d[1024 + i] = s1[i];
            }
            __syncthreads();
#pragma unroll
            for (int kk = 0; kk < 16; ++kk) {
                short8 bf0 = *(const short8*)(hstage + kk * 1024 + lane * 16);
                short8 bf1 = *(const short8*)(hstage + 16384 + kk * 1024 + lane * 16);
                const int c = ph * 16 + kk;
                a00 = __builtin_amdgcn_mfma_f32_16x16x32_bf16(awreg[0][c], bf0, a00, 0, 0, 0);
                a01 = __builtin_amdgcn_mfma_f32_16x16x32_bf16(awreg[0][c], bf1, a01, 0, 0, 0);
                a10 = __builtin_amdgcn_mfma_f32_16x16x32_bf16(awreg[1][c], bf0, a10, 0, 0, 0);
                a11 = __builtin_amdgcn_mfma_f32_16x16x32_bf16(awreg[1][c], bf1, a11, 0, 0, 0);
            }
            __syncthreads();
        }

        // C/D (HW-verified): col = lane&15, row = (lane>>4)*4 + reg
        {
            const int cn = lane & 15;
            const int rb = (lane >> 4) * 4;
#pragma unroll
            for (int r = 0; r < 4; ++r) {
                zbuf[wave][ 0 + rb + r][ 0 + cn] = a00[r];
                zbuf[wave][ 0 + rb + r][16 + cn] = a01[r];
                zbuf[wave][16 + rb + r][ 0 + cn] = a10[r];
                zbuf[wave][16 + rb + r][16 + cn] = a11[r];
            }
        }
        __syncthreads();

        // ---- elementwise epilogue: j = j0+4*aa+q, b = b0+nn ----
        const float xv = x[(b0 + nn) * T + t];
        unsigned short hb[4];
#pragma unroll
        for (int q = 0; q < 4; ++q) {
            const int jl = 4 * aa + q;
            float zg = zbuf[0][jl][nn] + wxl[0][jl] * xv + bsl[0][nn];
            float zi = zbuf[1][jl][nn] + wxl[1][jl] * xv + bsl[1][nn];
            float zf = zbuf[2][jl][nn] + wxl[2][jl] * xv + bsl[2][nn];
            float zo = zbuf[3][jl][nn] + wxl[3][jl] * xv + bsl[3][nn];
            float g  = tanhf(zg);
            float ig = 1.f / (1.f + expf(-zi));
            float fg = 1.f / (1.f + expf(-zf));
            float og = 1.f / (1.f + expf(-zo));
            creg[q] = g * ig + creg[q] * fg;
            float hn = tanhf(creg[q]) * og;
            hb[q] = bf16_bits(hn);
            if (t == T - 1) hfin[(j0 + jl) * B + (b0 + nn)] = hn;
        }
        // pack 4 consecutive-j bf16 -> one 8B store into next frag buffer
        {
            const unsigned lo = (unsigned)hb[0] | ((unsigned)hb[1] << 16);
            const unsigned hi = (unsigned)hb[2] | ((unsigned)hb[3] << 16);
            short* fb = (short*)(frag + ((t + 1) & 1) * 524288);
            short* fdst = fb + ((2 * bt + (nn >> 4)) * 32 + jt) * 512
                        + ((aa >> 1) * 16 + (nn & 15)) * 8 + (aa & 1) * 4;
            *(uint2*)fdst = make_uint2(lo, hi);
        }

        // ---- arrive: drain ALL waves' stores, then flag (release, agent) ----
        __threadfence();
        __syncthreads();
        if (tid == 0)
            __hip_atomic_fetch_add(myc, 1u, __ATOMIC_RELEASE, __HIP_MEMORY_SCOPE_AGENT);
    }
}

// ---------------- projection + softmax over batch --------------------------
__global__ __launch_bounds__(256) void lstm_final(
    const float* __restrict__ Wph, const float* __restrict__ hfin,
    const float* __restrict__ bp, float* __restrict__ out)
{
    __shared__ float sh[256];
    __shared__ float shm, shs;
    int c = blockIdx.x;
    int b = threadIdx.x;
    float acc = bp[b];
    const float* wr = Wph + c * H;
    for (int k = 0; k < H; ++k)
        acc += wr[k] * hfin[k * B + b];

    sh[b] = acc;
    __syncthreads();
    for (int s = 128; s > 0; s >>= 1) {
        if (b < s) sh[b] = fmaxf(sh[b], sh[b + s]);
        __syncthreads();
    }
    if (b == 0) shm = sh[0];
    __syncthreads();
    float e = expf(acc - shm);
    sh[b] = e;
    __syncthreads();
    for (int s = 128; s > 0; s >>= 1) {
        if (b < s) sh[b] += sh[b + s];
        __syncthreads();
    }
    if (b == 0) shs = sh[0];
    __syncthreads();
    out[b * NCLS + c] = e / shs;
}

extern "C" void kernel_launch(void* const* d_in, const int* in_sizes, int n_in,
                              void* d_out, int out_size, void* d_ws, size_t ws_size,
                              hipStream_t stream)
{
    const float* x   = (const float*)d_in[0];
    const float* Wgx = (const float*)d_in[1];
    const float* Wgh = (const float*)d_in[2];
    const float* Wix = (const float*)d_in[3];
    const float* Wih = (const float*)d_in[4];
    const float* Wfx = (const float*)d_in[5];
    const float* Wfh = (const float*)d_in[6];
    const float* Wox = (const float*)d_in[7];
    const float* Woh = (const float*)d_in[8];
    const float* Wph = (const float*)d_in[9];
    const float* bg  = (const float*)d_in[10];
    const float* bi  = (const float*)d_in[11];
    const float* bfv = (const float*)d_in[12];
    const float* bo  = (const float*)d_in[13];
    const float* bp  = (const float*)d_in[14];

    char* ws = (char*)d_ws;
    char* frag = ws;                                 // 1 MB (2 x 512 KB)
    unsigned* cnt = (unsigned*)(ws + 1048576);       // 4 KB
    float* hfin = (float*)(ws + 1052672);            // 1 MB

    hipMemsetAsync(frag, 0, 524288, stream);         // h_0 = 0
    hipMemsetAsync(cnt, 0, 4096, stream);            // barrier counters

    lstm_persist<<<256, 256, 0, stream>>>(
        x, Wgh, Wih, Wfh, Woh, Wgx, Wix, Wfx, Wox,
        bg, bi, bfv, bo, frag, cnt, hfin);

    lstm_final<<<NCLS, 256, 0, stream>>>(Wph, hfin, bp, (float*)d_out);
}

// Round 6
// 3297.894 us; speedup vs baseline: 2.3024x; 2.3024x over previous
//
#include <hip/hip_runtime.h>
#include <hip/hip_bf16.h>

// LSTM H=1024, B=256, T=256, C=10 — round 6.
// Round 5 passed but 29.6 us/step: VGPR_Count=192 proves awreg[2][32]
// (256 VGPRs) spilled to scratch (vector-addressable file caps at 256) and
// the per-step reload chain dominated. Fix:
// - 8 waves/WG (512 thr): wave = (gate = w&3, khalf = w>>2); each wave holds
//   W for 32 rows x K=512 = awreg[2][16] = 128 VGPRs -> no spill
//   (__launch_bounds__(512,2) caps at 256).
// - Full 64 KB h-slice staged to LDS once per step (single phase).
// - k-half partial z combined via padded LDS zb[2][4][32][36] (<=2-way banks).
// - Producer release: __syncthreads (drains vmcnt for all waves) + tid0
//   release-fetch_add only (round 5's extra per-wave __threadfence removed).
// Compute core fragment maps: HW-verified 16x16x32, round-1/5-proven.

#define H 1024
#define B 256
#define T 256
#define NCLS 10

typedef __attribute__((ext_vector_type(8))) short short8;   // 8 bf16
typedef __attribute__((ext_vector_type(4))) float f32x4;

__device__ inline unsigned short bf16_bits(float f) {
    union { __hip_bfloat16 h; unsigned short u; } cv;
    cv.h = __float2bfloat16(f);
    return cv.u;
}

// h frag layout (per 512 KB buffer), 16x16x32 B-frag order:
//   short index of (j in [0,1024), b in [0,256)):
//   ((b>>4)*32 + (j>>5))*512 + (((j>>3)&3)*16 + (b&15))*8 + (j&7)

__global__ __launch_bounds__(512, 2) void lstm_persist(
    const float* __restrict__ x,
    const float* __restrict__ Wgh, const float* __restrict__ Wih,
    const float* __restrict__ Wfh, const float* __restrict__ Woh,
    const float* __restrict__ Wgx, const float* __restrict__ Wix,
    const float* __restrict__ Wfx, const float* __restrict__ Wox,
    const float* __restrict__ bg, const float* __restrict__ bi,
    const float* __restrict__ bf_, const float* __restrict__ bo,
    char* __restrict__ frag,            // 2 x 524288 bytes
    unsigned* __restrict__ cnt,         // 8 group counters, 128 B apart
    float* __restrict__ hfin)           // H x B fp32
{
    __shared__ __align__(16) char hstage[65536];   // full bt h-slice (64 KB)
    __shared__ float zb[2][4][32][36];             // [khalf][gate][row][col+pad]
    __shared__ float wxl[4][32];
    __shared__ float bsl[4][32];

    const int tid  = threadIdx.x;
    const int lane = tid & 63;
    const int wave = tid >> 6;          // 0..7
    const int gate = wave & 3;
    const int kh   = wave >> 2;         // k-half: k in [512*kh, 512*kh+512)
    const int bt = blockIdx.x & 7;      // column group (XCD-local heuristic)
    const int jt = blockIdx.x >> 3;
    const int j0 = jt * 32;
    const int b0 = bt * 32;

    if (tid < 128) {
        int g = tid >> 5, r = tid & 31;
        const float* wx = (g == 0) ? Wgx : (g == 1) ? Wix : (g == 2) ? Wfx : Wox;
        const float* bb = (g == 0) ? bg  : (g == 1) ? bi  : (g == 2) ? bf_ : bo;
        wxl[g][r] = wx[j0 + r];
        bsl[g][r] = bb[b0 + r];
    }

    // ---- one-time: W gate tile -> registers, 16x16x32 A-fragment order ----
    // A map (HW-verified): lane holds A[m=lane&15][k = cg*32 + (lane>>4)*8 + i]
    // This wave covers chunks cg = kh*16 + c, c in [0,16), rows j0+16*mt+(lane&15).
    const float* Wh = (gate == 0) ? Wgh : (gate == 1) ? Wih : (gate == 2) ? Wfh : Woh;
    short8 awreg[2][16];
#pragma unroll
    for (int mt = 0; mt < 2; ++mt) {
        const float* wrow = Wh + (j0 + 16 * mt + (lane & 15)) * H
                          + kh * 512 + ((lane >> 4) * 8);
#pragma unroll
        for (int c = 0; c < 16; ++c) {
            const float4 f0 = *(const float4*)(wrow + c * 32);
            const float4 f1 = *(const float4*)(wrow + c * 32 + 4);
            short8 s;
            s[0] = (short)bf16_bits(f0.x); s[1] = (short)bf16_bits(f0.y);
            s[2] = (short)bf16_bits(f0.z); s[3] = (short)bf16_bits(f0.w);
            s[4] = (short)bf16_bits(f1.x); s[5] = (short)bf16_bits(f1.y);
            s[6] = (short)bf16_bits(f1.z); s[7] = (short)bf16_bits(f1.w);
            awreg[mt][c] = s;
        }
    }

    float creg[2] = {0.f, 0.f};
    const int nn = tid & 31;       // epilogue column  (b = b0+nn)
    const int aa = tid >> 5;       // epilogue j-pair  (j = j0+2*aa+q), aa in [0,16)
    unsigned* myc = &cnt[bt * 32];

    for (int t = 0; t < T; ++t) {
        // x load has no dependency on the barrier — issue early, use in epilogue
        const float xv = x[(b0 + nn) * T + t];

        // ---- wait: all 32 WGs of this bt-group finished step t-1 ----
        if (tid == 0) {
            const unsigned target = 32u * (unsigned)t;
            while (__hip_atomic_load(myc, __ATOMIC_ACQUIRE, __HIP_MEMORY_SCOPE_AGENT) < target)
                __builtin_amdgcn_s_sleep(2);
        }
        __syncthreads();

        // ---- stage the full 64 KB bt h-slice (linear copy) ----
        {
            const short8* gs = (const short8*)(frag + (t & 1) * 524288 + bt * 65536);
            short8* d = (short8*)hstage;
            for (int i = tid; i < 4096; i += 512) d[i] = gs[i];
        }
        __syncthreads();

        // ---- MFMA: 32 rows x 32 cols x K=512 per wave ----
        f32x4 a00 = {0.f,0.f,0.f,0.f}, a01 = a00, a10 = a00, a11 = a00;
#pragma unroll
        for (int c = 0; c < 16; ++c) {
            const int cg = kh * 16 + c;
            short8 bf0 = *(const short8*)(hstage + cg * 1024 + lane * 16);
            short8 bf1 = *(const short8*)(hstage + 32768 + cg * 1024 + lane * 16);
            a00 = __builtin_amdgcn_mfma_f32_16x16x32_bf16(awreg[0][c], bf0, a00, 0, 0, 0);
            a01 = __builtin_amdgcn_mfma_f32_16x16x32_bf16(awreg[0][c], bf1, a01, 0, 0, 0);
            a10 = __builtin_amdgcn_mfma_f32_16x16x32_bf16(awreg[1][c], bf0, a10, 0, 0, 0);
            a11 = __builtin_amdgcn_mfma_f32_16x16x32_bf16(awreg[1][c], bf1, a11, 0, 0, 0);
        }

        // C/D (HW-verified): col = lane&15, row = (lane>>4)*4 + reg
        {
            const int cn = lane & 15;
            const int rb = (lane >> 4) * 4;
#pragma unroll
            for (int r = 0; r < 4; ++r) {
                zb[kh][gate][ 0 + rb + r][ 0 + cn] = a00[r];
                zb[kh][gate][ 0 + rb + r][16 + cn] = a01[r];
                zb[kh][gate][16 + rb + r][ 0 + cn] = a10[r];
                zb[kh][gate][16 + rb + r][16 + cn] = a11[r];
            }
        }
        __syncthreads();

        // ---- elementwise epilogue: 2 cells/thread (j = j0+2*aa+q, b = b0+nn)
        unsigned short hb[2];
#pragma unroll
        for (int q = 0; q < 2; ++q) {
            const int jl = 2 * aa + q;
            float zg = (zb[0][0][jl][nn] + zb[1][0][jl][nn]) + wxl[0][jl] * xv + bsl[0][nn];
            float zi = (zb[0][1][jl][nn] + zb[1][1][jl][nn]) + wxl[1][jl] * xv + bsl[1][nn];
            float zf = (zb[0][2][jl][nn] + zb[1][2][jl][nn]) + wxl[2][jl] * xv + bsl[2][nn];
            float zo = (zb[0][3][jl][nn] + zb[1][3][jl][nn]) + wxl[3][jl] * xv + bsl[3][nn];
            float g  = tanhf(zg);
            float ig = 1.f / (1.f + expf(-zi));
            float fg = 1.f / (1.f + expf(-zf));
            float og = 1.f / (1.f + expf(-zo));
            creg[q] = g * ig + creg[q] * fg;
            float hn = tanhf(creg[q]) * og;
            hb[q] = bf16_bits(hn);
            if (t == T - 1) hfin[(j0 + jl) * B + (b0 + nn)] = hn;
        }
        // pack the 2 consecutive-j bf16 -> one 4 B store into next frag buffer
        // j = j0+2aa+q: j>>5 = jt, (j>>3)&3 = aa>>2, j&7 = 2*(aa&3)+q
        {
            const unsigned val = (unsigned)hb[0] | ((unsigned)hb[1] << 16);
            short* fb = (short*)(frag + ((t + 1) & 1) * 524288);
            short* fdst = fb + ((2 * bt + (nn >> 4)) * 32 + jt) * 512
                        + ((aa >> 2) * 16 + (nn & 15)) * 8 + (aa & 3) * 2;
            *(unsigned*)fdst = val;
        }

        // ---- arrive: syncthreads drains every wave's stores (vmcnt(0) before
        // s_barrier), then ONE release-add performs the L2 writeback + flag ----
        __syncthreads();
        if (tid == 0)
            __hip_atomic_fetch_add(myc, 1u, __ATOMIC_RELEASE, __HIP_MEMORY_SCOPE_AGENT);
    }
}

// ---------------- projection + softmax over batch --------------------------
__global__ __launch_bounds__(256) void lstm_final(
    const float* __restrict__ Wph, const float* __restrict__ hfin,
    const float* __restrict__ bp, float* __restrict__ out)
{
    __shared__ float sh[256];
    __shared__ float shm, shs;
    int c = blockIdx.x;
    int b = threadIdx.x;
    float acc = bp[b];
    const float* wr = Wph + c * H;
    for (int k = 0; k < H; ++k)
        acc += wr[k] * hfin[k * B + b];

    sh[b] = acc;
    __syncthreads();
    for (int s = 128; s > 0; s >>= 1) {
        if (b < s) sh[b] = fmaxf(sh[b], sh[b + s]);
        __syncthreads();
    }
    if (b == 0) shm = sh[0];
    __syncthreads();
    float e = expf(acc - shm);
    sh[b] = e;
    __syncthreads();
    for (int s = 128; s > 0; s >>= 1) {
        if (b < s) sh[b] += sh[b + s];
        __syncthreads();
    }
    if (b == 0) shs = sh[0];
    __syncthreads();
    out[b * NCLS + c] = e / shs;
}

extern "C" void kernel_launch(void* const* d_in, const int* in_sizes, int n_in,
                              void* d_out, int out_size, void* d_ws, size_t ws_size,
                              hipStream_t stream)
{
    const float* x   = (const float*)d_in[0];
    const float* Wgx = (const float*)d_in[1];
    const float* Wgh = (const float*)d_in[2];
    const float* Wix = (const float*)d_in[3];
    const float* Wih = (const float*)d_in[4];
    const float* Wfx = (const float*)d_in[5];
    const float* Wfh = (const float*)d_in[6];
    const float* Wox = (const float*)d_in[7];
    const float* Woh = (const float*)d_in[8];
    const float* Wph = (const float*)d_in[9];
    const float* bg  = (const float*)d_in[10];
    const float* bi  = (const float*)d_in[11];
    const float* bfv = (const float*)d_in[12];
    const float* bo  = (const float*)d_in[13];
    const float* bp  = (const float*)d_in[14];

    char* ws = (char*)d_ws;
    char* frag = ws;                                 // 1 MB (2 x 512 KB)
    unsigned* cnt = (unsigned*)(ws + 1048576);       // 4 KB
    float* hfin = (float*)(ws + 1052672);            // 1 MB

    hipMemsetAsync(frag, 0, 524288, stream);         // h_0 = 0
    hipMemsetAsync(cnt, 0, 4096, stream);            // barrier counters

    lstm_persist<<<256, 512, 0, stream>>>(
        x, Wgh, Wih, Wfh, Woh, Wgx, Wix, Wfx, Wox,
        bg, bi, bfv, bo, frag, cnt, hfin);

    lstm_final<<<NCLS, 256, 0, stream>>>(Wph, hfin, bp, (float*)d_out);
}

// Round 7
// 3196.550 us; speedup vs baseline: 2.3754x; 1.0317x over previous
//
#include <hip/hip_runtime.h>
#include <hip/hip_bf16.h>

// LSTM H=1024, B=256, T=256, C=10 — round 7.
// Round 6: VGPR_Count=104 < 128 needed for awreg => compiler SANK the W
// loads into the t-loop (const/restrict loads are rematerializable), so W
// (~64 MB/step device-wide) re-streamed from L3 every step -> 12.9 us/step,
// MfmaUtil 6.8%. Fix (single variable): pin the 32 W fragments with an
// opaque empty inline-asm ("+v") after init — kills remat, forces residency.
// Budget: 128 (W) + ~104 (working) = ~232 <= 256 @ __launch_bounds__(512,2).
// Everything else identical to round 6 (passed, absmax 1.5e-5).

#define H 1024
#define B 256
#define T 256
#define NCLS 10

typedef __attribute__((ext_vector_type(8))) short short8;   // 8 bf16
typedef __attribute__((ext_vector_type(4))) float f32x4;

__device__ inline unsigned short bf16_bits(float f) {
    union { __hip_bfloat16 h; unsigned short u; } cv;
    cv.h = __float2bfloat16(f);
    return cv.u;
}

// h frag layout (per 512 KB buffer), 16x16x32 B-frag order:
//   short index of (j in [0,1024), b in [0,256)):
//   ((b>>4)*32 + (j>>5))*512 + (((j>>3)&3)*16 + (b&15))*8 + (j&7)

__global__ __launch_bounds__(512, 2) void lstm_persist(
    const float* __restrict__ x,
    const float* __restrict__ Wgh, const float* __restrict__ Wih,
    const float* __restrict__ Wfh, const float* __restrict__ Woh,
    const float* __restrict__ Wgx, const float* __restrict__ Wix,
    const float* __restrict__ Wfx, const float* __restrict__ Wox,
    const float* __restrict__ bg, const float* __restrict__ bi,
    const float* __restrict__ bf_, const float* __restrict__ bo,
    char* __restrict__ frag,            // 2 x 524288 bytes
    unsigned* __restrict__ cnt,         // 8 group counters, 128 B apart
    float* __restrict__ hfin)           // H x B fp32
{
    __shared__ __align__(16) char hstage[65536];   // full bt h-slice (64 KB)
    __shared__ float zb[2][4][32][36];             // [khalf][gate][row][col+pad]
    __shared__ float wxl[4][32];
    __shared__ float bsl[4][32];

    const int tid  = threadIdx.x;
    const int lane = tid & 63;
    const int wave = tid >> 6;          // 0..7
    const int gate = wave & 3;
    const int kh   = wave >> 2;         // k-half: k in [512*kh, 512*kh+512)
    const int bt = blockIdx.x & 7;      // column group (XCD-local heuristic)
    const int jt = blockIdx.x >> 3;
    const int j0 = jt * 32;
    const int b0 = bt * 32;

    if (tid < 128) {
        int g = tid >> 5, r = tid & 31;
        const float* wx = (g == 0) ? Wgx : (g == 1) ? Wix : (g == 2) ? Wfx : Wox;
        const float* bb = (g == 0) ? bg  : (g == 1) ? bi  : (g == 2) ? bf_ : bo;
        wxl[g][r] = wx[j0 + r];
        bsl[g][r] = bb[b0 + r];
    }

    // ---- one-time: W gate tile -> registers, 16x16x32 A-fragment order ----
    // A map (HW-verified): lane holds A[m=lane&15][k = cg*32 + (lane>>4)*8 + i]
    // This wave covers chunks cg = kh*16 + c, c in [0,16), rows j0+16*mt+(lane&15).
    const float* Wh = (gate == 0) ? Wgh : (gate == 1) ? Wih : (gate == 2) ? Wfh : Woh;
    short8 awreg[2][16];
#pragma unroll
    for (int mt = 0; mt < 2; ++mt) {
        const float* wrow = Wh + (j0 + 16 * mt + (lane & 15)) * H
                          + kh * 512 + ((lane >> 4) * 8);
#pragma unroll
        for (int c = 0; c < 16; ++c) {
            const float4 f0 = *(const float4*)(wrow + c * 32);
            const float4 f1 = *(const float4*)(wrow + c * 32 + 4);
            short8 s;
            s[0] = (short)bf16_bits(f0.x); s[1] = (short)bf16_bits(f0.y);
            s[2] = (short)bf16_bits(f0.z); s[3] = (short)bf16_bits(f0.w);
            s[4] = (short)bf16_bits(f1.x); s[5] = (short)bf16_bits(f1.y);
            s[6] = (short)bf16_bits(f1.z); s[7] = (short)bf16_bits(f1.w);
            awreg[mt][c] = s;
        }
    }
    // ---- PIN: make fragment values opaque (no remat/sink) -> must stay in
    // registers for the whole kernel. This is the round-7 single variable.
#pragma unroll
    for (int mt = 0; mt < 2; ++mt)
#pragma unroll
        for (int c = 0; c < 16; ++c)
            __asm__ volatile("" : "+v"(awreg[mt][c]));

    float creg[2] = {0.f, 0.f};
    const int nn = tid & 31;       // epilogue column  (b = b0+nn)
    const int aa = tid >> 5;       // epilogue j-pair  (j = j0+2*aa+q), aa in [0,16)
    unsigned* myc = &cnt[bt * 32];

    for (int t = 0; t < T; ++t) {
        // x load has no dependency on the barrier — issue early, use in epilogue
        const float xv = x[(b0 + nn) * T + t];

        // ---- wait: all 32 WGs of this bt-group finished step t-1 ----
        if (tid == 0) {
            const unsigned target = 32u * (unsigned)t;
            while (__hip_atomic_load(myc, __ATOMIC_ACQUIRE, __HIP_MEMORY_SCOPE_AGENT) < target)
                __builtin_amdgcn_s_sleep(2);
        }
        __syncthreads();

        // ---- stage the full 64 KB bt h-slice (linear copy) ----
        {
            const short8* gs = (const short8*)(frag + (t & 1) * 524288 + bt * 65536);
            short8* d = (short8*)hstage;
            for (int i = tid; i < 4096; i += 512) d[i] = gs[i];
        }
        __syncthreads();

        // ---- MFMA: 32 rows x 32 cols x K=512 per wave ----
        f32x4 a00 = {0.f,0.f,0.f,0.f}, a01 = a00, a10 = a00, a11 = a00;
#pragma unroll
        for (int c = 0; c < 16; ++c) {
            const int cg = kh * 16 + c;
            short8 bf0 = *(const short8*)(hstage + cg * 1024 + lane * 16);
            short8 bf1 = *(const short8*)(hstage + 32768 + cg * 1024 + lane * 16);
            a00 = __builtin_amdgcn_mfma_f32_16x16x32_bf16(awreg[0][c], bf0, a00, 0, 0, 0);
            a01 = __builtin_amdgcn_mfma_f32_16x16x32_bf16(awreg[0][c], bf1, a01, 0, 0, 0);
            a10 = __builtin_amdgcn_mfma_f32_16x16x32_bf16(awreg[1][c], bf0, a10, 0, 0, 0);
            a11 = __builtin_amdgcn_mfma_f32_16x16x32_bf16(awreg[1][c], bf1, a11, 0, 0, 0);
        }

        // C/D (HW-verified): col = lane&15, row = (lane>>4)*4 + reg
        {
            const int cn = lane & 15;
            const int rb = (lane >> 4) * 4;
#pragma unroll
            for (int r = 0; r < 4; ++r) {
                zb[kh][gate][ 0 + rb + r][ 0 + cn] = a00[r];
                zb[kh][gate][ 0 + rb + r][16 + cn] = a01[r];
                zb[kh][gate][16 + rb + r][ 0 + cn] = a10[r];
                zb[kh][gate][16 + rb + r][16 + cn] = a11[r];
            }
        }
        __syncthreads();

        // ---- elementwise epilogue: 2 cells/thread (j = j0+2*aa+q, b = b0+nn)
        unsigned short hb[2];
#pragma unroll
        for (int q = 0; q < 2; ++q) {
            const int jl = 2 * aa + q;
            float zg = (zb[0][0][jl][nn] + zb[1][0][jl][nn]) + wxl[0][jl] * xv + bsl[0][nn];
            float zi = (zb[0][1][jl][nn] + zb[1][1][jl][nn]) + wxl[1][jl] * xv + bsl[1][nn];
            float zf = (zb[0][2][jl][nn] + zb[1][2][jl][nn]) + wxl[2][jl] * xv + bsl[2][nn];
            float zo = (zb[0][3][jl][nn] + zb[1][3][jl][nn]) + wxl[3][jl] * xv + bsl[3][nn];
            float g  = tanhf(zg);
            float ig = 1.f / (1.f + expf(-zi));
            float fg = 1.f / (1.f + expf(-zf));
            float og = 1.f / (1.f + expf(-zo));
            creg[q] = g * ig + creg[q] * fg;
            float hn = tanhf(creg[q]) * og;
            hb[q] = bf16_bits(hn);
            if (t == T - 1) hfin[(j0 + jl) * B + (b0 + nn)] = hn;
        }
        // pack the 2 consecutive-j bf16 -> one 4 B store into next frag buffer
        // j = j0+2aa+q: j>>5 = jt, (j>>3)&3 = aa>>2, j&7 = 2*(aa&3)+q
        {
            const unsigned val = (unsigned)hb[0] | ((unsigned)hb[1] << 16);
            short* fb = (short*)(frag + ((t + 1) & 1) * 524288);
            short* fdst = fb + ((2 * bt + (nn >> 4)) * 32 + jt) * 512
                        + ((aa >> 2) * 16 + (nn & 15)) * 8 + (aa & 3) * 2;
            *(unsigned*)fdst = val;
        }

        // ---- arrive: syncthreads drains every wave's stores (vmcnt(0) before
        // s_barrier), then ONE release-add performs the L2 writeback + flag ----
        __syncthreads();
        if (tid == 0)
            __hip_atomic_fetch_add(myc, 1u, __ATOMIC_RELEASE, __HIP_MEMORY_SCOPE_AGENT);
    }
}

// ---------------- projection + softmax over batch --------------------------
__global__ __launch_bounds__(256) void lstm_final(
    const float* __restrict__ Wph, const float* __restrict__ hfin,
    const float* __restrict__ bp, float* __restrict__ out)
{
    __shared__ float sh[256];
    __shared__ float shm, shs;
    int c = blockIdx.x;
    int b = threadIdx.x;
    float acc = bp[b];
    const float* wr = Wph + c * H;
    for (int k = 0; k < H; ++k)
        acc += wr[k] * hfin[k * B + b];

    sh[b] = acc;
    __syncthreads();
    for (int s = 128; s > 0; s >>= 1) {
        if (b < s) sh[b] = fmaxf(sh[b], sh[b + s]);
        __syncthreads();
    }
    if (b == 0) shm = sh[0];
    __syncthreads();
    float e = expf(acc - shm);
    sh[b] = e;
    __syncthreads();
    for (int s = 128; s > 0; s >>= 1) {
        if (b < s) sh[b] += sh[b + s];
        __syncthreads();
    }
    if (b == 0) shs = sh[0];
    __syncthreads();
    out[b * NCLS + c] = e / shs;
}

extern "C" void kernel_launch(void* const* d_in, const int* in_sizes, int n_in,
                              void* d_out, int out_size, void* d_ws, size_t ws_size,
                              hipStream_t stream)
{
    const float* x   = (const float*)d_in[0];
    const float* Wgx = (const float*)d_in[1];
    const float* Wgh = (const float*)d_in[2];
    const float* Wix = (const float*)d_in[3];
    const float* Wih = (const float*)d_in[4];
    const float* Wfx = (const float*)d_in[5];
    const float* Wfh = (const float*)d_in[6];
    const float* Wox = (const float*)d_in[7];
    const float* Woh = (const float*)d_in[8];
    const float* Wph = (const float*)d_in[9];
    const float* bg  = (const float*)d_in[10];
    const float* bi  = (const float*)d_in[11];
    const float* bfv = (const float*)d_in[12];
    const float* bo  = (const float*)d_in[13];
    const float* bp  = (const float*)d_in[14];

    char* ws = (char*)d_ws;
    char* frag = ws;                                 // 1 MB (2 x 512 KB)
    unsigned* cnt = (unsigned*)(ws + 1048576);       // 4 KB
    float* hfin = (float*)(ws + 1052672);            // 1 MB

    hipMemsetAsync(frag, 0, 524288, stream);         // h_0 = 0
    hipMemsetAsync(cnt, 0, 4096, stream);            // barrier counters

    lstm_persist<<<256, 512, 0, stream>>>(
        x, Wgh, Wih, Wfh, Woh, Wgx, Wix, Wfx, Wox,
        bg, bi, bfv, bo, frag, cnt, hfin);

    lstm_final<<<NCLS, 256, 0, stream>>>(Wph, hfin, bp, (float*)d_out);
}